// Round 2
// baseline (107.095 us; speedup 1.0000x reference)
//
#include <hip/hip_runtime.h>
#include <stdint.h>

#define NB 4096     // B
#define ND 256      // D

typedef __attribute__((ext_vector_type(8))) short short8;   // 8 bf16 = 4 VGPR
typedef __attribute__((ext_vector_type(4))) float f32x4;

// fp32 -> bf16 RNE (inputs are finite Gaussians; no NaN handling needed)
__device__ __forceinline__ unsigned short f2bf(float f) {
    unsigned int u = __float_as_uint(f);
    u += 0x7FFFu + ((u >> 16) & 1u);
    return (unsigned short)(u >> 16);
}

// async global->LDS, 16B per lane. lds dest = wave-uniform base + lane*16.
__device__ __forceinline__ void gload16(const void* g, void* lds_uniform) {
    __builtin_amdgcn_global_load_lds(
        (const __attribute__((address_space(1))) void*)(uintptr_t)g,
        (__attribute__((address_space(3))) void*)(unsigned int)(uintptr_t)lds_uniform,
        16, 0, 0);
}

// ---------------- prep: 1/||row||, bf16 copies, zero loss accumulator ----------------
__global__ void __launch_bounds__(256) prep_kernel(
    const float* __restrict__ A, const float* __restrict__ Bf,
    unsigned short* __restrict__ Abf, unsigned short* __restrict__ Bbf,
    float* __restrict__ rna, float* __restrict__ rnb, float* __restrict__ lossws)
{
    if (blockIdx.x == 0 && threadIdx.x == 0) lossws[0] = 0.0f;
    int gw   = (blockIdx.x * 256 + threadIdx.x) >> 6;   // global wave id 0..8191
    int lane = threadIdx.x & 63;
    const float* src; unsigned short* dst; float* rn; int row;
    if (gw < NB) { src = A;  dst = Abf; rn = rna; row = gw; }
    else         { src = Bf; dst = Bbf; rn = rnb; row = gw - NB; }

    float4 v = reinterpret_cast<const float4*>(src + (size_t)row * ND)[lane];
    float ss = v.x * v.x + v.y * v.y + v.z * v.z + v.w * v.w;
    #pragma unroll
    for (int off = 32; off > 0; off >>= 1) ss += __shfl_down(ss, off);
    if (lane == 0) rn[row] = 1.0f / sqrtf(fmaxf(ss, 1e-30f));

    ushort4 u;
    u.x = f2bf(v.x); u.y = f2bf(v.y); u.z = f2bf(v.z); u.w = f2bf(v.w);
    reinterpret_cast<ushort4*>(dst + (size_t)row * ND)[lane] = u;
}

// ---------------- fused GEMM + diagonal-permuted epilogue + BCE loss ----------------
// Block: 128x128 (k,j) tile, 4 waves (2x2), each wave a 64x64 subtile.
// BK=32, double-buffered staging (2x16KB). Epilogue reroutes acc through a
// wave-private diagonal-bijective LDS region (8KB/wave, two 32-diag-row passes)
// so global stores are contiguous runs of out[s*NB + k].
__global__ void __launch_bounds__(256, 5) gemm_kernel(
    const unsigned short* __restrict__ Abf, const unsigned short* __restrict__ Bbf,
    const float* __restrict__ rna, const float* __restrict__ rnb,
    const float* __restrict__ labels, float* __restrict__ out,
    float* __restrict__ lossws)
{
    __shared__ __align__(16) char smem[32768]; // dbuf staging 2x(A 8K + B 8K); epilogue 4x8K

    const int tid = threadIdx.x;
    const int w = tid >> 6, lane = tid & 63;
    const int lane15 = lane & 15, lhi = lane >> 4;
    const int bk = blockIdx.x >> 5, bj = blockIdx.x & 31;
    const int k0 = bk << 7, j0 = bj << 7;
    const int mw = w >> 1, nw = w & 1;

    f32x4 acc[4][4];
    #pragma unroll
    for (int i = 0; i < 4; ++i)
        #pragma unroll
        for (int j = 0; j < 4; ++j) acc[i][j] = (f32x4)0.0f;

    // stage K-chunk kt (BK=32) into buffer cur. A chunk = 128 rows x 64B = 512
    // 16B-slots; wave w covers slots [w*128, w*128+128) = rows [w*32, w*32+32).
    auto stage = [&](int kt, int cur) {
        char* bufA = smem + (cur << 14);
        char* bufB = bufA + 8192;
        #pragma unroll
        for (int i = 0; i < 2; ++i) {
            int slot0 = (w << 7) + (i << 6);  // wave-uniform
            int slot  = slot0 + lane;
            int row   = slot >> 2;            // 4 slots of 16B per 64B row
            int sch   = (slot & 3) ^ (row & 3); // pre-swizzled source chunk
            gload16(Abf + (size_t)(k0 + row) * ND + kt * 32 + sch * 8, bufA + slot0 * 16);
            gload16(Bbf + (size_t)(j0 + row) * ND + kt * 32 + sch * 8, bufB + slot0 * 16);
        }
    };

    stage(0, 0);
    __syncthreads();   // drains vmcnt(0): buf0 ready

    int cur = 0;
    for (int kt = 0; kt < 8; ++kt) {          // K = 256 in 8 chunks of BK=32
        if (kt < 7) stage(kt + 1, cur ^ 1);   // prefetch overlaps compute below
        char* bufA = smem + (cur << 14);
        char* bufB = bufA + 8192;
        short8 af[4], bfr[4];
        #pragma unroll
        for (int mi = 0; mi < 4; ++mi) {
            int row = (mw << 6) + (mi << 4) + lane15;
            int ch  = lhi ^ (row & 3);
            af[mi] = *reinterpret_cast<const short8*>(bufA + row * 64 + ch * 16);
        }
        #pragma unroll
        for (int ni = 0; ni < 4; ++ni) {
            int row = (nw << 6) + (ni << 4) + lane15;
            int ch  = lhi ^ (row & 3);
            bfr[ni] = *reinterpret_cast<const short8*>(bufB + row * 64 + ch * 16);
        }
        #pragma unroll
        for (int mi = 0; mi < 4; ++mi)
            #pragma unroll
            for (int ni = 0; ni < 4; ++ni)
                acc[mi][ni] = __builtin_amdgcn_mfma_f32_16x16x32_bf16(
                    af[mi], bfr[ni], acc[mi][ni], 0, 0, 0);
        __syncthreads();   // vmcnt(0): next buffer staged; lgkm: all reads done
        cur ^= 1;
    }

    // ---- epilogue: acc -> diagonal LDS (wave-private, two 32-row passes) ----
    // element (kappa, iota): diag dr=(iota-kappa)&63, stored at
    // dwave[(dr&31)][kappa ^ (dr&31)] during pass dr>>5. No barriers needed:
    // same-wave DS ops are in-order.
    float* dwave = reinterpret_cast<float*>(smem) + (w << 11); // 8KB per wave
    const int kw0 = k0 + (mw << 6);
    const int jw0 = j0 + (nw << 6);
    const float rna_l = rna[kw0 + lane];
    const float rnb_l = rnb[jw0 + lane];
    const float lab_l = labels[kw0 + lane];
    const int sbase = (jw0 - kw0 + NB) & (NB - 1);

    float lacc = 0.0f;
    #pragma unroll
    for (int pass = 0; pass < 2; ++pass) {
        #pragma unroll
        for (int mi = 0; mi < 4; ++mi)
            #pragma unroll
            for (int ni = 0; ni < 4; ++ni)
                #pragma unroll
                for (int e = 0; e < 4; ++e) {
                    int kap = (mi << 4) + (lhi << 2) + e;   // local k (C/D row)
                    int io  = (ni << 4) + lane15;           // local j (C/D col)
                    int dr  = (io - kap) & 63;
                    if ((dr >> 5) == pass)
                        dwave[((dr & 31) << 6) + (kap ^ (dr & 31))] = acc[mi][ni][e];
                }
        #pragma unroll 8
        for (int r = 0; r < 32; ++r) {
            int rr = (pass << 5) | r;
            // LDS row r holds diagonal rr: logical column kappa = lane
            float d = dwave[(r << 6) + (lane ^ r)];
            int wrap = ((lane + rr) >> 6) & 1;                  // iota wrapped past 64
            int s = (sbase + rr - (wrap << 6) + NB) & (NB - 1); // global shift index
            float rnbv = __shfl(rnb_l, (lane + rr) & 63);
            float cosv = d * rna_l * rnbv;
            float x = fmaf(cosv, 0.5f, 0.5f);                   // logit in (0,1)
            out[(size_t)s * NB + (kw0 + lane)] = x;             // 2 contiguous segments
            float l1p = fmaxf(__logf(1.0f - x), -100.0f);
            if (s == 0) {
                float lp = fmaxf(__logf(x), -100.0f);
                lacc += lab_l * lp + (1.0f - lab_l) * l1p;      // weight 1
            } else {
                lacc += 0.5f * l1p;                             // weight NEG_WEIGHT
            }
        }
    }
    #pragma unroll
    for (int off = 32; off > 0; off >>= 1) lacc += __shfl_down(lacc, off);
    if (lane == 0) atomicAdd(lossws, -lacc);
}

__global__ void finalize_kernel(const float* __restrict__ lossws, float* __restrict__ out) {
    out[(size_t)NB * NB] = lossws[0];
}

extern "C" void kernel_launch(void* const* d_in, const int* in_sizes, int n_in,
                              void* d_out, int out_size, void* d_ws, size_t ws_size,
                              hipStream_t stream) {
    (void)in_sizes; (void)n_in; (void)out_size; (void)ws_size;
    const float* A      = (const float*)d_in[0];
    const float* Bf     = (const float*)d_in[1];
    const float* labels = (const float*)d_in[2];
    float* out = (float*)d_out;

    char* ws = (char*)d_ws;
    unsigned short* Abf = (unsigned short*)ws;                                  // 2 MB
    unsigned short* Bbf = (unsigned short*)(ws + (size_t)2 * 1024 * 1024);      // 2 MB
    float* rna    = (float*)(ws + (size_t)4 * 1024 * 1024);                     // 16 KB
    float* rnb    = (float*)(ws + (size_t)4 * 1024 * 1024 + 16384);             // 16 KB
    float* lossws = (float*)(ws + (size_t)4 * 1024 * 1024 + 32768);             // 4 B

    hipLaunchKernelGGL(prep_kernel, dim3(2048), dim3(256), 0, stream,
                       A, Bf, Abf, Bbf, rna, rnb, lossws);
    hipLaunchKernelGGL(gemm_kernel, dim3(1024), dim3(256), 0, stream,
                       Abf, Bbf, rna, rnb, labels, out, lossws);
    hipLaunchKernelGGL(finalize_kernel, dim3(1), dim3(1), 0, stream, lossws, out);
}

// Round 3
// 84.994 us; speedup vs baseline: 1.2600x; 1.2600x over previous
//
#include <hip/hip_runtime.h>
#include <stdint.h>

#define NB 4096     // B
#define ND 256      // D

typedef __attribute__((ext_vector_type(8))) short short8;   // 8 bf16 = 4 VGPR
typedef __attribute__((ext_vector_type(4))) float f32x4;

// fp32 -> bf16 RNE (inputs are finite Gaussians; no NaN handling needed)
__device__ __forceinline__ unsigned short f2bf(float f) {
    unsigned int u = __float_as_uint(f);
    u += 0x7FFFu + ((u >> 16) & 1u);
    return (unsigned short)(u >> 16);
}

// async global->LDS, 16B per lane. lds dest = wave-uniform base + lane*16.
__device__ __forceinline__ void gload16(const void* g, void* lds_uniform) {
    __builtin_amdgcn_global_load_lds(
        (const __attribute__((address_space(1))) void*)(uintptr_t)g,
        (__attribute__((address_space(3))) void*)(unsigned int)(uintptr_t)lds_uniform,
        16, 0, 0);
}

// ---------------- prep: 1/||row||, bf16 copies, zero loss accumulator ----------------
__global__ void __launch_bounds__(256) prep_kernel(
    const float* __restrict__ A, const float* __restrict__ Bf,
    unsigned short* __restrict__ Abf, unsigned short* __restrict__ Bbf,
    float* __restrict__ rna, float* __restrict__ rnb, float* __restrict__ lossws)
{
    if (blockIdx.x == 0 && threadIdx.x == 0) lossws[0] = 0.0f;
    int gw   = (blockIdx.x * 256 + threadIdx.x) >> 6;   // global wave id 0..8191
    int lane = threadIdx.x & 63;
    const float* src; unsigned short* dst; float* rn; int row;
    if (gw < NB) { src = A;  dst = Abf; rn = rna; row = gw; }
    else         { src = Bf; dst = Bbf; rn = rnb; row = gw - NB; }

    float4 v = reinterpret_cast<const float4*>(src + (size_t)row * ND)[lane];
    float ss = v.x * v.x + v.y * v.y + v.z * v.z + v.w * v.w;
    #pragma unroll
    for (int off = 32; off > 0; off >>= 1) ss += __shfl_down(ss, off);
    if (lane == 0) rn[row] = 1.0f / sqrtf(fmaxf(ss, 1e-30f));

    ushort4 u;
    u.x = f2bf(v.x); u.y = f2bf(v.y); u.z = f2bf(v.z); u.w = f2bf(v.w);
    reinterpret_cast<ushort4*>(dst + (size_t)row * ND)[lane] = u;
}

// ---------------- fused banded GEMM + row-owned epilogue + BCE loss ----------------
// Block (bk,bs) OWNS out rows s in [s0,s0+128), cols k in [k0,k0+128):
// contiguous 512B row segments, float4 stores, zero partial-line sharing.
// Needs dots[k][k+s] = staircase band: B-rows j in [k0+s0, k0+s0+256).
// 4 waves; wave w handles k-strips {2w,2w+1} (32 k-rows), 10 shared B-frags,
// 18 MFMA per K=32 step (1.125x overcompute vs exact band).
__global__ void __launch_bounds__(256, 3) gemm_kernel(
    const unsigned short* __restrict__ Abf, const unsigned short* __restrict__ Bbf,
    const float* __restrict__ rna, const float* __restrict__ rnb,
    const float* __restrict__ labels, float* __restrict__ out,
    float* __restrict__ lossws)
{
    __shared__ __align__(16) char smem[49152]; // A 16K | B 32K ; epi: dw 16K | rnb 1K | rna 0.5K

    const int tid = threadIdx.x;
    const int w = tid >> 6, lane = tid & 63;
    const int lane15 = lane & 15, lhi = lane >> 4;
    const int bk = blockIdx.x & 31, bs = blockIdx.x >> 5;
    const int k0 = bk << 7, s0 = bs << 7;
    const int j0 = (k0 + s0) & (NB - 1);

    char* ldsA = smem;            // 128 rows x 128B (BK=64 bf16)
    char* ldsB = smem + 16384;    // 256 rows x 128B

    f32x4 acc[2][9];
    #pragma unroll
    for (int st = 0; st < 2; ++st)
        #pragma unroll
        for (int r = 0; r < 9; ++r) acc[st][r] = (f32x4)0.0f;

    for (int kt = 0; kt < 4; ++kt) {          // K = 256 in 4 chunks of BK=64
        // stage A: 1024 16B-slots (4/wave-iter), pre-swizzled source chunk
        #pragma unroll
        for (int i = 0; i < 4; ++i) {
            int slot0 = (i << 8) + (w << 6);  // wave-uniform
            int slot  = slot0 + lane;
            int row   = slot >> 3;            // 8 chunks of 16B per 128B row
            int sch   = (slot & 7) ^ (row & 7);
            gload16(Abf + (size_t)(k0 + row) * ND + (kt << 6) + (sch << 3), ldsA + slot0 * 16);
        }
        // stage B: 2048 slots, rows j0..j0+255 (mod NB)
        #pragma unroll
        for (int i = 0; i < 8; ++i) {
            int slot0 = (i << 8) + (w << 6);
            int slot  = slot0 + lane;
            int row   = slot >> 3;            // 0..255
            int srow  = (j0 + row) & (NB - 1);
            int sch   = (slot & 7) ^ (row & 7);
            gload16(Bbf + (size_t)srow * ND + (kt << 6) + (sch << 3), ldsB + slot0 * 16);
        }
        __syncthreads();   // drains vmcnt: buffers ready

        #pragma unroll
        for (int ks = 0; ks < 2; ++ks) {      // two K=32 MFMA steps per BK=64
            short8 af[2], bfr[10];
            #pragma unroll
            for (int st = 0; st < 2; ++st) {
                int row = (w << 5) + (st << 4) + lane15;
                int ch  = ((ks << 2) + lhi) ^ (row & 7);
                af[st] = *reinterpret_cast<const short8*>(ldsA + row * 128 + ch * 16);
            }
            #pragma unroll
            for (int ni = 0; ni < 10; ++ni) {
                int row = (w << 5) + (ni << 4) + lane15;
                int ch  = ((ks << 2) + lhi) ^ (row & 7);
                bfr[ni] = *reinterpret_cast<const short8*>(ldsB + row * 128 + ch * 16);
            }
            #pragma unroll
            for (int st = 0; st < 2; ++st)
                #pragma unroll
                for (int r = 0; r < 9; ++r)
                    acc[st][r] = __builtin_amdgcn_mfma_f32_16x16x32_bf16(
                        af[st], bfr[st + r], acc[st][r], 0, 0, 0);
        }
        __syncthreads();   // all reads done; staging reusable
    }

    // ---- epilogue: 4 chunks of 32 out-rows, via XOR-swizzled LDS bounce ----
    float* dw      = reinterpret_cast<float*>(smem);          // 32 x 128 f32 (16K)
    float* rnb_lds = reinterpret_cast<float*>(smem + 16384);  // 256 f32
    float* rna_lds = reinterpret_cast<float*>(smem + 17408);  // 128 f32
    rnb_lds[tid] = rnb[(j0 + tid) & (NB - 1)];
    if (tid < 128) rna_lds[tid] = rna[k0 + tid];

    const int q = lane & 31, rh = lane >> 5;
    float lacc = 0.0f;

    #pragma unroll
    for (int c = 0; c < 4; ++c) {
        // scatter: element (st,r,e): block-local k = kg, out-row t = 16r+jl-4lhi-e
        // only r in {2c, 2c+1, 2c+2} can land in rows [32c, 32c+32)
        #pragma unroll
        for (int st = 0; st < 2; ++st)
            #pragma unroll
            for (int rr = 0; rr < 3; ++rr) {
                int r = 2 * c + rr;
                #pragma unroll
                for (int e = 0; e < 4; ++e) {
                    int kg = (w << 5) + (st << 4) + (lhi << 2) + e;
                    int t  = (r << 4) + lane15 - (lhi << 2) - e;
                    if (t >= (c << 5) && t < (c << 5) + 32)
                        dw[((t & 31) << 7) + (kg ^ ((t & 31) << 2))] = acc[st][r][e];
                }
            }
        __syncthreads();

        // read rows, fused cos->logit->store(float4)->loss. wave w: rows [8w,8w+8)
        #pragma unroll
        for (int i = 0; i < 4; ++i) {
            int row = (w << 3) + (i << 1) + rh;               // 0..31 (chunk-local)
            int colbase = (q << 2) ^ (row << 2);              // column permutation
            f32x4 d = *reinterpret_cast<f32x4*>(dw + (row << 7) + (q << 2));
            int t = (c << 5) + row;                           // out-row - s0
            int s = s0 + t;
            f32x4 na = *reinterpret_cast<f32x4*>(rna_lds + colbase);
            f32x4 x;
            #pragma unroll
            for (int e = 0; e < 4; ++e) {
                float rb = rnb_lds[colbase + e + t];          // j-local = kg + t < 256
                x[e] = fmaf(d[e] * na[e] * rb, 0.5f, 0.5f);   // logit in (0,1)
            }
            *reinterpret_cast<f32x4*>(out + (size_t)s * NB + k0 + colbase) = x;
            float l1p0 = fmaxf(__logf(1.0f - x[0]), -100.0f);
            float l1p1 = fmaxf(__logf(1.0f - x[1]), -100.0f);
            float l1p2 = fmaxf(__logf(1.0f - x[2]), -100.0f);
            float l1p3 = fmaxf(__logf(1.0f - x[3]), -100.0f);
            if (s == 0) {   // diagonal block row: weight 1, label from labels[]
                float l1pv[4] = {l1p0, l1p1, l1p2, l1p3};
                #pragma unroll
                for (int e = 0; e < 4; ++e) {
                    float lab = labels[k0 + colbase + e];
                    float lp  = fmaxf(__logf(x[e]), -100.0f);
                    lacc += lab * lp + (1.0f - lab) * l1pv[e];
                }
            } else {
                lacc += 0.5f * (l1p0 + l1p1 + l1p2 + l1p3);   // NEG_WEIGHT
            }
        }
        __syncthreads();   // dw reusable for next chunk
    }

    #pragma unroll
    for (int off = 32; off > 0; off >>= 1) lacc += __shfl_down(lacc, off);
    if (lane == 0) atomicAdd(lossws, -lacc);
}

__global__ void finalize_kernel(const float* __restrict__ lossws, float* __restrict__ out) {
    out[(size_t)NB * NB] = lossws[0];
}

extern "C" void kernel_launch(void* const* d_in, const int* in_sizes, int n_in,
                              void* d_out, int out_size, void* d_ws, size_t ws_size,
                              hipStream_t stream) {
    (void)in_sizes; (void)n_in; (void)out_size; (void)ws_size;
    const float* A      = (const float*)d_in[0];
    const float* Bf     = (const float*)d_in[1];
    const float* labels = (const float*)d_in[2];
    float* out = (float*)d_out;

    char* ws = (char*)d_ws;
    unsigned short* Abf = (unsigned short*)ws;                                  // 2 MB
    unsigned short* Bbf = (unsigned short*)(ws + (size_t)2 * 1024 * 1024);      // 2 MB
    float* rna    = (float*)(ws + (size_t)4 * 1024 * 1024);                     // 16 KB
    float* rnb    = (float*)(ws + (size_t)4 * 1024 * 1024 + 16384);             // 16 KB
    float* lossws = (float*)(ws + (size_t)4 * 1024 * 1024 + 32768);             // 4 B

    hipLaunchKernelGGL(prep_kernel, dim3(2048), dim3(256), 0, stream,
                       A, Bf, Abf, Bbf, rna, rnb, lossws);
    hipLaunchKernelGGL(gemm_kernel, dim3(1024), dim3(256), 0, stream,
                       Abf, Bbf, rna, rnb, labels, out, lossws);
    hipLaunchKernelGGL(finalize_kernel, dim3(1), dim3(1), 0, stream, lossws, out);
}

// Round 4
// 47.931 us; speedup vs baseline: 2.2344x; 1.7733x over previous
//
#include <hip/hip_runtime.h>
#include <stdint.h>

#define NB 4096     // B
#define ND 256      // D

typedef __attribute__((ext_vector_type(8))) short short8;   // 8 bf16 = 4 VGPR
typedef __attribute__((ext_vector_type(4))) float f32x4;

// fp32 -> bf16 RNE (inputs are finite Gaussians; no NaN handling needed)
__device__ __forceinline__ unsigned short f2bf(float f) {
    unsigned int u = __float_as_uint(f);
    u += 0x7FFFu + ((u >> 16) & 1u);
    return (unsigned short)(u >> 16);
}

// async global->LDS, 16B per lane. lds dest = wave-uniform base + lane*16.
__device__ __forceinline__ void gload16(const void* g, void* lds_uniform) {
    __builtin_amdgcn_global_load_lds(
        (const __attribute__((address_space(1))) void*)(uintptr_t)g,
        (__attribute__((address_space(3))) void*)(unsigned int)(uintptr_t)lds_uniform,
        16, 0, 0);
}

// ---------------- prep: 1/||row||, bf16 copies, zero loss cells ----------------
__global__ void __launch_bounds__(256) prep_kernel(
    const float* __restrict__ A, const float* __restrict__ Bf,
    unsigned short* __restrict__ Abf, unsigned short* __restrict__ Bbf,
    float* __restrict__ rna, float* __restrict__ rnb, float* __restrict__ lossws)
{
    if (blockIdx.x == 0 && threadIdx.x < 64) lossws[threadIdx.x << 5] = 0.0f;
    int gw   = (blockIdx.x * 256 + threadIdx.x) >> 6;   // global wave id 0..8191
    int lane = threadIdx.x & 63;
    const float* src; unsigned short* dst; float* rn; int row;
    if (gw < NB) { src = A;  dst = Abf; rn = rna; row = gw; }
    else         { src = Bf; dst = Bbf; rn = rnb; row = gw - NB; }

    float4 v = reinterpret_cast<const float4*>(src + (size_t)row * ND)[lane];
    float ss = v.x * v.x + v.y * v.y + v.z * v.z + v.w * v.w;
    #pragma unroll
    for (int off = 32; off > 0; off >>= 1) ss += __shfl_down(ss, off);
    if (lane == 0) rn[row] = 1.0f / sqrtf(fmaxf(ss, 1e-30f));

    ushort4 u;
    u.x = f2bf(v.x); u.y = f2bf(v.y); u.z = f2bf(v.z); u.w = f2bf(v.w);
    reinterpret_cast<ushort4*>(dst + (size_t)row * ND)[lane] = u;
}

// ---------------- fused banded GEMM + row-owned epilogue + BCE loss ----------------
// Block (bk,bs) OWNS out rows s in [s0,s0+64), cols k in [k0,k0+64):
// contiguous 256B row segments, float4 stores, zero partial-line sharing.
// Band: B-rows j in [k0+s0, k0+s0+128). 4 waves; wave w owns k-strip
// [16w,16w+16): 1 A-frag + 5 B-frags + 5 MFMA per K=32 step (1.25x overcompute).
// BK=32 double-buffered staging (2 x 12KB), one barrier per K-chunk.
__global__ void __launch_bounds__(256, 6) gemm_kernel(
    const unsigned short* __restrict__ Abf, const unsigned short* __restrict__ Bbf,
    const float* __restrict__ rna, const float* __restrict__ rnb,
    const float* __restrict__ labels, float* __restrict__ out,
    float* __restrict__ lossws)
{
    // buf0 [0,12288): A 4K | B 8K ; buf1 [12288,24576)
    // epilogue (after final sync): dw [0,16384) ; rnb 16384..16896 ; rna ..17152 ; lpart ..17168
    __shared__ __align__(16) char smem[24576];

    const int tid = threadIdx.x;
    const int w = tid >> 6, lane = tid & 63;
    const int lane15 = lane & 15, lhi = lane >> 4;
    const int bk = blockIdx.x & 63, bs = blockIdx.x >> 6;
    const int k0 = bk << 6, s0 = bs << 6;
    const int j0 = (k0 + s0) & (NB - 1);

    f32x4 acc[5];
    #pragma unroll
    for (int r = 0; r < 5; ++r) acc[r] = (f32x4)0.0f;

    // stage K-chunk kt (BK=32, 64B rows of 4x16B chunks) into buffer `buf`.
    // source chunk pre-swizzled: holds logical chunk (pc ^ f(row)), f=(row^(row>>2))&3
    auto stage = [&](int kt, char* buf) {
        {   // A: 64 rows -> 256 slots, 1 per lane
            int slot0 = w << 6;               // wave-uniform
            int slot  = slot0 + lane;
            int row   = slot >> 2;
            int sch   = (slot ^ (slot >> 2) ^ (slot >> 4)) & 3;
            gload16(Abf + (size_t)(k0 + row) * ND + (kt << 5) + (sch << 3), buf + slot0 * 16);
        }
        #pragma unroll
        for (int i = 0; i < 2; ++i) {         // B: 128 rows -> 512 slots, 2 per lane
            int slot0 = (i << 8) + (w << 6);
            int slot  = slot0 + lane;
            int row   = slot >> 2;
            int srow  = (j0 + row) & (NB - 1);
            int sch   = (slot ^ (slot >> 2) ^ (slot >> 4)) & 3;
            gload16(Bbf + (size_t)srow * ND + (kt << 5) + (sch << 3), buf + 4096 + slot0 * 16);
        }
    };

    stage(0, smem);
    __syncthreads();   // vmcnt(0): buf0 ready

    for (int kt = 0; kt < 8; ++kt) {          // K = 256 in 8 chunks of BK=32
        char* buf = smem + ((kt & 1) ? 12288 : 0);
        if (kt < 7) stage(kt + 1, smem + ((kt & 1) ? 0 : 12288));  // prefetch overlaps compute
        const int f = (lane15 ^ (lane15 >> 2)) & 3;   // = f(row) for all rows read below
        short8 af;
        {
            int row = (w << 4) + lane15;
            af = *reinterpret_cast<const short8*>(buf + row * 64 + ((lhi ^ f) << 4));
        }
        #pragma unroll
        for (int r = 0; r < 5; ++r) {
            int brow = (w << 4) + (r << 4) + lane15;
            short8 bfr = *reinterpret_cast<const short8*>(buf + 4096 + brow * 64 + ((lhi ^ f) << 4));
            acc[r] = __builtin_amdgcn_mfma_f32_16x16x32_bf16(af, bfr, acc[r], 0, 0, 0);
        }
        __syncthreads();   // all reads done; prefetched buffer landed
    }

    // ---- epilogue: acc -> XOR-swizzled LDS (64x64), then row-owned stores + loss ----
    float* dw      = reinterpret_cast<float*>(smem);          // 64 x 64 f32 (16K)
    float* rnb_lds = reinterpret_cast<float*>(smem + 16384);  // 128 f32
    float* rna_lds = reinterpret_cast<float*>(smem + 16896);  // 64 f32
    float* lpart   = reinterpret_cast<float*>(smem + 17152);  // 4 f32

    if (tid < 128) rnb_lds[tid] = rnb[(j0 + tid) & (NB - 1)];
    if (tid < 64)  rna_lds[tid] = rna[k0 + tid];

    // scatter: element (r,e): out-row t = 16r + lane15 - 4lhi - e, col kap (wave-private)
    #pragma unroll
    for (int r = 0; r < 5; ++r)
        #pragma unroll
        for (int e = 0; e < 4; ++e) {
            int t = (r << 4) + lane15 - (lhi << 2) - e;
            if ((unsigned)t < 64u) {
                int kap = (w << 4) + (lhi << 2) + e;
                dw[(t << 6) + (kap ^ ((t & 7) << 2))] = acc[r][e];
            }
        }
    __syncthreads();

    // read rows: wave w owns rows [16w,16w+16); 4 lanes x 4 float4 per row
    const int trow = (w << 4) + (lane >> 2);
    const int g0 = lane & 3;
    const int s = s0 + trow;
    float lacc = 0.0f;
    #pragma unroll
    for (int i = 0; i < 4; ++i) {
        int lg = (i << 2) + g0;                       // logical 4-col group
        int pg = lg ^ (trow & 7);                     // physical group (un-swizzle)
        f32x4 d  = *reinterpret_cast<f32x4*>(dw + (trow << 6) + (pg << 2));
        f32x4 na = *reinterpret_cast<f32x4*>(rna_lds + (lg << 2));
        f32x4 x;
        #pragma unroll
        for (int e = 0; e < 4; ++e) {
            float rb = rnb_lds[(lg << 2) + e + trow]; // j_local = kap + t < 128
            x[e] = fmaf(d[e] * na[e] * rb, 0.5f, 0.5f);   // logit in (0,1)
        }
        *reinterpret_cast<f32x4*>(out + (size_t)s * NB + k0 + (lg << 2)) = x;
        float l1p0 = fmaxf(__logf(1.0f - x[0]), -100.0f);
        float l1p1 = fmaxf(__logf(1.0f - x[1]), -100.0f);
        float l1p2 = fmaxf(__logf(1.0f - x[2]), -100.0f);
        float l1p3 = fmaxf(__logf(1.0f - x[3]), -100.0f);
        if (s == 0) {   // weight-1 labeled row
            float l1pv[4] = {l1p0, l1p1, l1p2, l1p3};
            #pragma unroll
            for (int e = 0; e < 4; ++e) {
                float lab = labels[k0 + (lg << 2) + e];
                float lp  = fmaxf(__logf(x[e]), -100.0f);
                lacc += lab * lp + (1.0f - lab) * l1pv[e];
            }
        } else {
            lacc += 0.5f * (l1p0 + l1p1 + l1p2 + l1p3);   // NEG_WEIGHT
        }
    }

    #pragma unroll
    for (int off = 32; off > 0; off >>= 1) lacc += __shfl_down(lacc, off);
    if (lane == 0) lpart[w] = lacc;
    __syncthreads();
    if (tid == 0) {
        float tot = lpart[0] + lpart[1] + lpart[2] + lpart[3];
        atomicAdd(lossws + ((blockIdx.x & 63) << 5), -tot);
    }
}

__global__ void finalize_kernel(const float* __restrict__ lossws, float* __restrict__ out) {
    float s = 0.0f;
    for (int i = 0; i < 64; ++i) s += lossws[i << 5];
    out[(size_t)NB * NB] = s;
}

extern "C" void kernel_launch(void* const* d_in, const int* in_sizes, int n_in,
                              void* d_out, int out_size, void* d_ws, size_t ws_size,
                              hipStream_t stream) {
    (void)in_sizes; (void)n_in; (void)out_size; (void)ws_size;
    const float* A      = (const float*)d_in[0];
    const float* Bf     = (const float*)d_in[1];
    const float* labels = (const float*)d_in[2];
    float* out = (float*)d_out;

    char* ws = (char*)d_ws;
    unsigned short* Abf = (unsigned short*)ws;                                  // 2 MB
    unsigned short* Bbf = (unsigned short*)(ws + (size_t)2 * 1024 * 1024);      // 2 MB
    float* rna    = (float*)(ws + (size_t)4 * 1024 * 1024);                     // 16 KB
    float* rnb    = (float*)(ws + (size_t)4 * 1024 * 1024 + 16384);             // 16 KB
    float* lossws = (float*)(ws + (size_t)4 * 1024 * 1024 + 32768);             // 8 KB (64 cells x 128B)

    hipLaunchKernelGGL(prep_kernel, dim3(2048), dim3(256), 0, stream,
                       A, Bf, Abf, Bbf, rna, rnb, lossws);
    hipLaunchKernelGGL(gemm_kernel, dim3(4096), dim3(256), 0, stream,
                       Abf, Bbf, rna, rnb, labels, out, lossws);
    hipLaunchKernelGGL(finalize_kernel, dim3(1), dim3(1), 0, stream, lossws, out);
}